// Round 1
// baseline (1691.492 us; speedup 1.0000x reference)
//
#include <hip/hip_runtime.h>
#include <hip/hip_bf16.h>

#define NN 50000
#define EE 1600000
#define DIM 256
#define KDIM 512
#define NLAYER 3

// ---------------- attention score: s_src = h @ w_src (one wave per node) ----------------
__global__ __launch_bounds__(256) void k_attn_scores(const float* __restrict__ h,
                                                     const float* __restrict__ w_src,
                                                     float* __restrict__ s_src) {
    int wave = threadIdx.x >> 6, lane = threadIdx.x & 63;
    int n = blockIdx.x * 4 + wave;
    if (n >= NN) return;
    const float4 hv = *reinterpret_cast<const float4*>(h + (size_t)n * DIM + lane * 4);
    const float4 wv = *reinterpret_cast<const float4*>(w_src + lane * 4);
    float ss = hv.x * wv.x + hv.y * wv.y + hv.z * wv.z + hv.w * wv.w;
    #pragma unroll
    for (int m = 32; m; m >>= 1) ss += __shfl_xor(ss, m);
    if (lane == 0) s_src[n] = ss;
}

// ---------------- CSR build ----------------
__global__ __launch_bounds__(256) void k_count_deg(const int* __restrict__ ei, int* __restrict__ deg) {
    int e = blockIdx.x * 256 + threadIdx.x;
    if (e < EE) atomicAdd(&deg[ei[EE + e]], 1);
}

__global__ __launch_bounds__(256) void k_scan1(const int* __restrict__ deg, int* __restrict__ exscan,
                                               int* __restrict__ blkSums) {
    __shared__ int tmp[256];
    int t = threadIdx.x;
    int i = blockIdx.x * 256 + t;
    int v = (i < NN) ? deg[i] : 0;
    int acc = v;
    tmp[t] = acc;
    __syncthreads();
    for (int off = 1; off < 256; off <<= 1) {
        int add = (t >= off) ? tmp[t - off] : 0;
        __syncthreads();
        acc += add;
        tmp[t] = acc;
        __syncthreads();
    }
    if (i < NN) exscan[i] = acc - v;          // exclusive scan within block
    if (t == 255) blkSums[blockIdx.x] = acc;  // block total
}

__global__ __launch_bounds__(256) void k_scan2(int* __restrict__ blkSums, int nblk) {
    __shared__ int tmp[256];
    int t = threadIdx.x;
    int v = (t < nblk) ? blkSums[t] : 0;
    int acc = v;
    tmp[t] = acc;
    __syncthreads();
    for (int off = 1; off < 256; off <<= 1) {
        int add = (t >= off) ? tmp[t - off] : 0;
        __syncthreads();
        acc += add;
        tmp[t] = acc;
        __syncthreads();
    }
    blkSums[t] = acc - v;  // exclusive
}

__global__ __launch_bounds__(256) void k_scan3(int* __restrict__ row_ptr, const int* __restrict__ blkSums,
                                               int* __restrict__ cursor) {
    int t = threadIdx.x;
    int i = blockIdx.x * 256 + t;
    if (i < NN) {
        int val = row_ptr[i] + blkSums[blockIdx.x];
        row_ptr[i] = val;
        cursor[i] = val;
    }
    if (i == 0) row_ptr[NN] = EE;
}

__global__ __launch_bounds__(256) void k_scatter(const int* __restrict__ ei, int* __restrict__ cursor,
                                                 int* __restrict__ csr_src) {
    int e = blockIdx.x * 256 + threadIdx.x;
    if (e < EE) {
        int s = ei[e];
        int d = ei[EE + e];
        int pos = atomicAdd(&cursor[d], 1);
        csr_src[pos] = s;
    }
}

// ---------------- pull-based attention aggregation (one wave per dst node) ----------------
// alpha_e = exp(s_src[src_e]) / sum_e' exp(s_src[src_e'])   (dst term + bias cancel in softmax)
__global__ __launch_bounds__(256) void k_aggregate(const float* __restrict__ h,
                                                   const float* __restrict__ s_src,
                                                   const int* __restrict__ row_ptr,
                                                   const int* __restrict__ csr_src,
                                                   float* __restrict__ agg) {
    int wave = threadIdx.x >> 6, lane = threadIdx.x & 63;
    int n = blockIdx.x * 4 + wave;
    if (n >= NN) return;
    int beg = row_ptr[n], end = row_ptr[n + 1];

    float ssum = 0.f;
    for (int e = beg + lane; e < end; e += 64) ssum += __expf(s_src[csr_src[e]]);
    #pragma unroll
    for (int m = 32; m; m >>= 1) ssum += __shfl_xor(ssum, m);
    float inv = (end > beg) ? 1.f / ssum : 0.f;

    float acc0 = 0.f, acc1 = 0.f, acc2 = 0.f, acc3 = 0.f;
    for (int e = beg; e < end; ++e) {
        int s = csr_src[e];                      // uniform across wave (broadcast)
        float w = __expf(s_src[s]) * inv;
        const float4 hv = *reinterpret_cast<const float4*>(h + (size_t)s * DIM + lane * 4);
        acc0 += w * hv.x; acc1 += w * hv.y; acc2 += w * hv.z; acc3 += w * hv.w;
    }
    float4 o = {acc0, acc1, acc2, acc3};
    *reinterpret_cast<float4*>(agg + (size_t)n * DIM + lane * 4) = o;
}

// ---------------- fp32 tiled GEMM: z = [hin|agg](N,512) @ W(512,256) + bias ----------------
#define BM 64
#define BN 64
#define BK 16
__global__ __launch_bounds__(256) void k_gemm(const float* __restrict__ hin,
                                              const float* __restrict__ agg,
                                              const float* __restrict__ W,
                                              const float* __restrict__ bias,
                                              float* __restrict__ z) {
    __shared__ float As[BK][BM + 4];
    __shared__ float Bs[BK][BN + 4];
    int t = threadIdx.x;
    int tx = t & 15, ty = t >> 4;
    int m0 = blockIdx.x * BM, n0 = blockIdx.y * BN;
    float acc[4][4] = {{0.f}};

    for (int kk = 0; kk < KDIM; kk += BK) {
        // stage A tile: rows m0..+63, cols kk..+15 of [hin|agg]
        {
            int j = t & 15;   // k within tile
            int i0 = t >> 4;  // row within tile
            const float* src = (kk + j < DIM) ? hin : agg;
            int kcol = (kk + j) & (DIM - 1);
            #pragma unroll
            for (int p = 0; p < 4; ++p) {
                int i = i0 + p * 16;
                int m = m0 + i;
                As[j][i] = (m < NN) ? src[(size_t)m * DIM + kcol] : 0.f;
            }
        }
        // stage B tile: rows kk..+15, cols n0..+63 of W
        {
            int c = t & 63, r0 = t >> 6;
            #pragma unroll
            for (int p = 0; p < 4; ++p) {
                int r = r0 + p * 4;
                Bs[r][c] = W[(size_t)(kk + r) * DIM + n0 + c];
            }
        }
        __syncthreads();
        #pragma unroll
        for (int k = 0; k < BK; ++k) {
            const float4 a = *reinterpret_cast<const float4*>(&As[k][ty * 4]);
            const float4 b = *reinterpret_cast<const float4*>(&Bs[k][tx * 4]);
            acc[0][0] += a.x * b.x; acc[0][1] += a.x * b.y; acc[0][2] += a.x * b.z; acc[0][3] += a.x * b.w;
            acc[1][0] += a.y * b.x; acc[1][1] += a.y * b.y; acc[1][2] += a.y * b.z; acc[1][3] += a.y * b.w;
            acc[2][0] += a.z * b.x; acc[2][1] += a.z * b.y; acc[2][2] += a.z * b.z; acc[2][3] += a.z * b.w;
            acc[3][0] += a.w * b.x; acc[3][1] += a.w * b.y; acc[3][2] += a.w * b.z; acc[3][3] += a.w * b.w;
        }
        __syncthreads();
    }

    #pragma unroll
    for (int i = 0; i < 4; ++i) {
        int m = m0 + ty * 4 + i;
        if (m >= NN) continue;
        #pragma unroll
        for (int j = 0; j < 4; ++j) {
            int n = n0 + tx * 4 + j;
            z[(size_t)m * DIM + n] = acc[i][j] + bias[n];
        }
    }
}

// ---------------- LayerNorm + ReLU, in place (one wave per row) ----------------
__global__ __launch_bounds__(256) void k_ln_relu(float* __restrict__ z,
                                                 const float* __restrict__ gamma_l,
                                                 const float* __restrict__ beta_l) {
    int wave = threadIdx.x >> 6, lane = threadIdx.x & 63;
    int n = blockIdx.x * 4 + wave;
    if (n >= NN) return;
    float4 v = *reinterpret_cast<float4*>(z + (size_t)n * DIM + lane * 4);
    float s = v.x + v.y + v.z + v.w;
    float s2 = v.x * v.x + v.y * v.y + v.z * v.z + v.w * v.w;
    #pragma unroll
    for (int m = 32; m; m >>= 1) { s += __shfl_xor(s, m); s2 += __shfl_xor(s2, m); }
    float mu = s * (1.f / DIM);
    float var = s2 * (1.f / DIM) - mu * mu;
    float rstd = rsqrtf(var + 1e-5f);
    const float4 g = *reinterpret_cast<const float4*>(gamma_l + lane * 4);
    const float4 b = *reinterpret_cast<const float4*>(beta_l + lane * 4);
    v.x = fmaxf(g.x * (v.x - mu) * rstd + b.x, 0.f);
    v.y = fmaxf(g.y * (v.y - mu) * rstd + b.y, 0.f);
    v.z = fmaxf(g.z * (v.z - mu) * rstd + b.z, 0.f);
    v.w = fmaxf(g.w * (v.w - mu) * rstd + b.w, 0.f);
    *reinterpret_cast<float4*>(z + (size_t)n * DIM + lane * 4) = v;
}

// ---------------- column sums ----------------
__global__ __launch_bounds__(256) void k_colsum(const float* __restrict__ mat, float* __restrict__ out) {
    int j = threadIdx.x;  // 256 cols
    float s = 0.f;
    for (int r = blockIdx.x; r < NN; r += gridDim.x) s += mat[(size_t)r * DIM + j];
    atomicAdd(&out[j], s);
}

// ---------------- final: out = mean(h) + mean(x) @ W_skip + b_skip ----------------
__global__ __launch_bounds__(256) void k_final(const float* __restrict__ hsum, const float* __restrict__ xsum,
                                               const float* __restrict__ W_skip, const float* __restrict__ b_skip,
                                               float* __restrict__ out) {
    int j = threadIdx.x;
    float acc = 0.f;
    const float invN = 1.f / (float)NN;
    for (int i = 0; i < DIM; ++i) acc += (xsum[i] * invN) * W_skip[(size_t)i * DIM + j];
    out[j] = hsum[j] * invN + acc + b_skip[j];
}

extern "C" void kernel_launch(void* const* d_in, const int* in_sizes, int n_in,
                              void* d_out, int out_size, void* d_ws, size_t ws_size,
                              hipStream_t stream) {
    const float* x      = (const float*)d_in[0];
    const int*   ei     = (const int*)d_in[1];
    const float* W_sage = (const float*)d_in[2];
    const float* b_sage = (const float*)d_in[3];
    const float* gamma  = (const float*)d_in[4];
    const float* beta   = (const float*)d_in[5];
    const float* W_attn = (const float*)d_in[6];
    // d_in[7] = b_attn: cancels in the per-dst softmax — unused.
    const float* W_skip = (const float*)d_in[8];
    const float* b_skip = (const float*)d_in[9];
    float* out = (float*)d_out;

    // workspace layout
    float* h_a    = (float*)d_ws;                     // NN*DIM
    float* h_b    = h_a + (size_t)NN * DIM;           // NN*DIM
    float* agg    = h_b + (size_t)NN * DIM;           // NN*DIM
    float* s_src  = agg + (size_t)NN * DIM;           // NN
    float* colsum = s_src + NN;                       // DIM
    float* xsum   = colsum + DIM;                     // DIM
    int*   row_ptr = (int*)(xsum + DIM);              // NN+1
    int*   cursor  = row_ptr + NN + 1;                // NN
    int*   blkSums = cursor + NN;                     // 256
    int*   csr_src = blkSums + 256;                   // EE

    const int NBLK_N = (NN + 255) / 256;   // 196
    const int NBLK_E = (EE + 255) / 256;   // 6250

    // zero degree counters and reduction accumulators (every call: graph replays)
    hipMemsetAsync(cursor, 0, (size_t)NN * sizeof(int), stream);
    hipMemsetAsync(colsum, 0, 2 * DIM * sizeof(float), stream);

    // CSR build (graph is layer-invariant: build once per call)
    k_count_deg<<<NBLK_E, 256, 0, stream>>>(ei, cursor);
    k_scan1<<<NBLK_N, 256, 0, stream>>>(cursor, row_ptr, blkSums);
    k_scan2<<<1, 256, 0, stream>>>(blkSums, NBLK_N);
    k_scan3<<<NBLK_N, 256, 0, stream>>>(row_ptr, blkSums, cursor);
    k_scatter<<<NBLK_E, 256, 0, stream>>>(ei, cursor, csr_src);

    const float* h_in = x;
    float* bufs[2] = {h_a, h_b};
    for (int l = 0; l < NLAYER; ++l) {
        float* h_out = bufs[l & 1];
        const float* w_src_l = W_attn + (size_t)l * KDIM + DIM;  // second half of W_attn[l]
        k_attn_scores<<<NN / 4, 256, 0, stream>>>(h_in, w_src_l, s_src);
        k_aggregate<<<NN / 4, 256, 0, stream>>>(h_in, s_src, row_ptr, csr_src, agg);
        k_gemm<<<dim3((NN + BM - 1) / BM, DIM / BN), 256, 0, stream>>>(
            h_in, agg, W_sage + (size_t)l * KDIM * DIM, b_sage + (size_t)l * DIM, h_out);
        k_ln_relu<<<NN / 4, 256, 0, stream>>>(h_out, gamma + (size_t)l * DIM, beta + (size_t)l * DIM);
        h_in = h_out;
    }

    k_colsum<<<256, 256, 0, stream>>>(h_in, colsum);
    k_colsum<<<256, 256, 0, stream>>>(x, xsum);
    k_final<<<1, 256, 0, stream>>>(colsum, xsum, W_skip, b_skip, out);
}

// Round 2
// 1031.839 us; speedup vs baseline: 1.6393x; 1.6393x over previous
//
#include <hip/hip_runtime.h>
#include <hip/hip_bf16.h>

#define NN 50000
#define EE 1600000
#define DIM 256
#define KDIM 512
#define NLAYER 3

using bf16x8 = __attribute__((ext_vector_type(8))) short;
using f32x4  = __attribute__((ext_vector_type(4))) float;

static __device__ __forceinline__ unsigned short f2bf(float f) {
    unsigned u = __builtin_bit_cast(unsigned, f);
    unsigned r = (u + 0x7FFFu + ((u >> 16) & 1u)) >> 16;   // RNE
    return (unsigned short)r;
}
static __device__ __forceinline__ float bf2f(unsigned short s) {
    return __builtin_bit_cast(float, (unsigned)s << 16);
}

// ---------------- prep: x (fp32) -> h0 (bf16), e_src0 = exp(x . w_src0) ----------------
__global__ __launch_bounds__(256) void k_prep(const float* __restrict__ x,
                                              const float* __restrict__ w_src,
                                              unsigned short* __restrict__ hout,
                                              float* __restrict__ e_src) {
    int wave = threadIdx.x >> 6, lane = threadIdx.x & 63;
    int n = blockIdx.x * 4 + wave;
    if (n >= NN) return;
    const float4 v = *reinterpret_cast<const float4*>(x + (size_t)n * DIM + lane * 4);
    const float4 wv = *reinterpret_cast<const float4*>(w_src + lane * 4);
    float sc = v.x * wv.x + v.y * wv.y + v.z * wv.z + v.w * wv.w;
    #pragma unroll
    for (int m = 32; m; m >>= 1) sc += __shfl_xor(sc, m);
    if (lane == 0) e_src[n] = __expf(sc);
    ushort4 o;
    o.x = f2bf(v.x); o.y = f2bf(v.y); o.z = f2bf(v.z); o.w = f2bf(v.w);
    *reinterpret_cast<ushort4*>(hout + (size_t)n * DIM + lane * 4) = o;
}

// ---------------- CSR build ----------------
__global__ __launch_bounds__(256) void k_count_deg(const int* __restrict__ ei, int* __restrict__ deg) {
    int e = blockIdx.x * 256 + threadIdx.x;
    if (e < EE) atomicAdd(&deg[ei[EE + e]], 1);
}

__global__ __launch_bounds__(256) void k_scan1(const int* __restrict__ deg, int* __restrict__ exscan,
                                               int* __restrict__ blkSums) {
    __shared__ int tmp[256];
    int t = threadIdx.x;
    int i = blockIdx.x * 256 + t;
    int v = (i < NN) ? deg[i] : 0;
    int acc = v;
    tmp[t] = acc;
    __syncthreads();
    for (int off = 1; off < 256; off <<= 1) {
        int add = (t >= off) ? tmp[t - off] : 0;
        __syncthreads();
        acc += add;
        tmp[t] = acc;
        __syncthreads();
    }
    if (i < NN) exscan[i] = acc - v;
    if (t == 255) blkSums[blockIdx.x] = acc;
}

__global__ __launch_bounds__(256) void k_scan2(int* __restrict__ blkSums, int nblk) {
    __shared__ int tmp[256];
    int t = threadIdx.x;
    int v = (t < nblk) ? blkSums[t] : 0;
    int acc = v;
    tmp[t] = acc;
    __syncthreads();
    for (int off = 1; off < 256; off <<= 1) {
        int add = (t >= off) ? tmp[t - off] : 0;
        __syncthreads();
        acc += add;
        tmp[t] = acc;
        __syncthreads();
    }
    blkSums[t] = acc - v;
}

__global__ __launch_bounds__(256) void k_scan3(int* __restrict__ row_ptr, const int* __restrict__ blkSums,
                                               int* __restrict__ cursor) {
    int t = threadIdx.x;
    int i = blockIdx.x * 256 + t;
    if (i < NN) {
        int val = row_ptr[i] + blkSums[blockIdx.x];
        row_ptr[i] = val;
        cursor[i] = val;
    }
    if (i == 0) row_ptr[NN] = EE;
}

__global__ __launch_bounds__(256) void k_scatter(const int* __restrict__ ei, int* __restrict__ cursor,
                                                 int* __restrict__ csr_src) {
    int e = blockIdx.x * 256 + threadIdx.x;
    if (e < EE) {
        int s = ei[e];
        int d = ei[EE + e];
        int pos = atomicAdd(&cursor[d], 1);
        csr_src[pos] = s;
    }
}

// ---------------- single-pass attention aggregation (one wave per dst node) ----------------
// weight_e = e_src[src_e]; agg = (sum_e w_e * h[src_e]) / (sum_e w_e)
// denominator is lane-identical -> no cross-lane reduce needed.
__global__ __launch_bounds__(256) void k_aggregate(const unsigned short* __restrict__ h,
                                                   const float* __restrict__ e_src,
                                                   const int* __restrict__ row_ptr,
                                                   const int* __restrict__ csr_src,
                                                   unsigned short* __restrict__ agg) {
    int wave = threadIdx.x >> 6, lane = threadIdx.x & 63;
    int n = blockIdx.x * 4 + wave;
    if (n >= NN) return;
    int beg = row_ptr[n], end = row_ptr[n + 1];

    float a0 = 0.f, a1 = 0.f, a2 = 0.f, a3 = 0.f, den = 0.f;
    for (int e = beg; e < end; ++e) {
        int s = csr_src[e];                          // wave-uniform -> broadcast loads
        float w = e_src[s];
        ushort4 hv = *reinterpret_cast<const ushort4*>(h + (size_t)s * DIM + lane * 4);
        a0 += w * bf2f(hv.x); a1 += w * bf2f(hv.y);
        a2 += w * bf2f(hv.z); a3 += w * bf2f(hv.w);
        den += w;
    }
    float inv = (end > beg) ? 1.f / den : 0.f;
    ushort4 o;
    o.x = f2bf(a0 * inv); o.y = f2bf(a1 * inv); o.z = f2bf(a2 * inv); o.w = f2bf(a3 * inv);
    *reinterpret_cast<ushort4*>(agg + (size_t)n * DIM + lane * 4) = o;
}

// ---------------- pack W (fp32 [512][256]) -> Bp bf16, MFMA-B-fragment-linear ----------------
// Bp element index = ((ks*16 + nf)*16 + c)*32 + q*8 + j  holds  W[ks*32 + q*8 + j][nf*16 + c]
__global__ __launch_bounds__(256) void k_packB(const float* __restrict__ W, unsigned short* __restrict__ Bp) {
    int tid = blockIdx.x * 256 + threadIdx.x;   // 0 .. 131071
    int j  = tid & 7;
    int q  = (tid >> 3) & 3;
    int c  = (tid >> 5) & 15;
    int nf = (tid >> 9) & 15;
    int ks = tid >> 13;
    Bp[tid] = f2bf(W[(size_t)(ks * 32 + q * 8 + j) * DIM + nf * 16 + c]);
}

// ---------------- MFMA GEMM: z = [h|agg](N,512)_bf16 @ Bp + bias -> fp32 ----------------
// block = 4 waves; wave tile = 32 rows x 128 cols; grid = (ceil(N/128), 2)
__global__ __launch_bounds__(256) void k_gemm_mfma(const unsigned short* __restrict__ hin,
                                                   const unsigned short* __restrict__ agg,
                                                   const unsigned short* __restrict__ Bp,
                                                   const float* __restrict__ bias,
                                                   float* __restrict__ z) {
    int w = threadIdx.x >> 6, lane = threadIdx.x & 63;
    int c = lane & 15, q = lane >> 4;
    int m0 = blockIdx.x * 128 + w * 32;
    int n0 = blockIdx.y * 128;
    int nf0 = n0 >> 4;

    f32x4 acc[2][8];
    #pragma unroll
    for (int nf = 0; nf < 8; ++nf) {
        float b = bias[n0 + nf * 16 + c];
        acc[0][nf] = (f32x4){b, b, b, b};
        acc[1][nf] = (f32x4){b, b, b, b};
    }

    #pragma unroll
    for (int ks = 0; ks < 16; ++ks) {
        const int kk = ks * 32;
        const unsigned short* hsrc = (kk < DIM) ? hin : agg;
        const int kcol = (kk & (DIM - 1)) + q * 8;
        bf16x8 a0 = *reinterpret_cast<const bf16x8*>(hsrc + (size_t)(m0 + c) * DIM + kcol);
        bf16x8 a1 = *reinterpret_cast<const bf16x8*>(hsrc + (size_t)(m0 + 16 + c) * DIM + kcol);
        #pragma unroll
        for (int nf = 0; nf < 8; ++nf) {
            bf16x8 bfr = *reinterpret_cast<const bf16x8*>(
                Bp + ((size_t)((ks * 16 + nf0 + nf) * 16 + c)) * 32 + q * 8);
            acc[0][nf] = __builtin_amdgcn_mfma_f32_16x16x32_bf16(a0, bfr, acc[0][nf], 0, 0, 0);
            acc[1][nf] = __builtin_amdgcn_mfma_f32_16x16x32_bf16(a1, bfr, acc[1][nf], 0, 0, 0);
        }
    }

    #pragma unroll
    for (int mf = 0; mf < 2; ++mf) {
        #pragma unroll
        for (int r = 0; r < 4; ++r) {
            int row = m0 + mf * 16 + q * 4 + r;
            if (row < NN) {
                #pragma unroll
                for (int nf = 0; nf < 8; ++nf)
                    z[(size_t)row * DIM + n0 + nf * 16 + c] = acc[mf][nf][r];
            }
        }
    }
}

// ---------------- LayerNorm + ReLU + bf16 pack + next-layer exp-score ----------------
__global__ __launch_bounds__(256) void k_ln_relu(const float* __restrict__ z,
                                                 const float* __restrict__ gamma_l,
                                                 const float* __restrict__ beta_l,
                                                 const float* __restrict__ w_src_next,  // may be null
                                                 unsigned short* __restrict__ hout,
                                                 float* __restrict__ e_src) {
    int wave = threadIdx.x >> 6, lane = threadIdx.x & 63;
    int n = blockIdx.x * 4 + wave;
    if (n >= NN) return;
    float4 v = *reinterpret_cast<const float4*>(z + (size_t)n * DIM + lane * 4);
    float s = v.x + v.y + v.z + v.w;
    float s2 = v.x * v.x + v.y * v.y + v.z * v.z + v.w * v.w;
    #pragma unroll
    for (int m = 32; m; m >>= 1) { s += __shfl_xor(s, m); s2 += __shfl_xor(s2, m); }
    float mu = s * (1.f / DIM);
    float var = s2 * (1.f / DIM) - mu * mu;
    float rstd = rsqrtf(var + 1e-5f);
    const float4 g = *reinterpret_cast<const float4*>(gamma_l + lane * 4);
    const float4 b = *reinterpret_cast<const float4*>(beta_l + lane * 4);
    v.x = fmaxf(g.x * (v.x - mu) * rstd + b.x, 0.f);
    v.y = fmaxf(g.y * (v.y - mu) * rstd + b.y, 0.f);
    v.z = fmaxf(g.z * (v.z - mu) * rstd + b.z, 0.f);
    v.w = fmaxf(g.w * (v.w - mu) * rstd + b.w, 0.f);

    if (w_src_next) {
        const float4 wv = *reinterpret_cast<const float4*>(w_src_next + lane * 4);
        float sc = v.x * wv.x + v.y * wv.y + v.z * wv.z + v.w * wv.w;
        #pragma unroll
        for (int m = 32; m; m >>= 1) sc += __shfl_xor(sc, m);
        if (lane == 0) e_src[n] = __expf(sc);
    }
    ushort4 o;
    o.x = f2bf(v.x); o.y = f2bf(v.y); o.z = f2bf(v.z); o.w = f2bf(v.w);
    *reinterpret_cast<ushort4*>(hout + (size_t)n * DIM + lane * 4) = o;
}

// ---------------- column sums ----------------
__global__ __launch_bounds__(256) void k_colsum_f32(const float* __restrict__ mat, float* __restrict__ out) {
    int j = threadIdx.x;
    float s = 0.f;
    for (int r = blockIdx.x; r < NN; r += gridDim.x) s += mat[(size_t)r * DIM + j];
    atomicAdd(&out[j], s);
}
__global__ __launch_bounds__(256) void k_colsum_bf16(const unsigned short* __restrict__ mat,
                                                     float* __restrict__ out) {
    int j = threadIdx.x;
    float s = 0.f;
    for (int r = blockIdx.x; r < NN; r += gridDim.x) s += bf2f(mat[(size_t)r * DIM + j]);
    atomicAdd(&out[j], s);
}

// ---------------- final: out = mean(h) + mean(x) @ W_skip + b_skip ----------------
__global__ __launch_bounds__(256) void k_final(const float* __restrict__ hsum, const float* __restrict__ xsum,
                                               const float* __restrict__ W_skip, const float* __restrict__ b_skip,
                                               float* __restrict__ out) {
    int j = threadIdx.x;
    float acc = 0.f;
    const float invN = 1.f / (float)NN;
    for (int i = 0; i < DIM; ++i) acc += (xsum[i] * invN) * W_skip[(size_t)i * DIM + j];
    out[j] = hsum[j] * invN + acc + b_skip[j];
}

extern "C" void kernel_launch(void* const* d_in, const int* in_sizes, int n_in,
                              void* d_out, int out_size, void* d_ws, size_t ws_size,
                              hipStream_t stream) {
    const float* x      = (const float*)d_in[0];
    const int*   ei     = (const int*)d_in[1];
    const float* W_sage = (const float*)d_in[2];
    const float* b_sage = (const float*)d_in[3];
    const float* gamma  = (const float*)d_in[4];
    const float* beta   = (const float*)d_in[5];
    const float* W_attn = (const float*)d_in[6];
    // d_in[7] = b_attn: cancels in the per-dst softmax — unused.
    const float* W_skip = (const float*)d_in[8];
    const float* b_skip = (const float*)d_in[9];
    float* out = (float*)d_out;

    // ---- workspace layout ----
    const size_t ND = (size_t)NN * DIM;
    unsigned short* hx   = (unsigned short*)d_ws;        // ND bf16
    unsigned short* hA   = hx + ND;                      // ND bf16
    unsigned short* hB   = hA + ND;                      // ND bf16
    unsigned short* agg  = hB + ND;                      // ND bf16
    unsigned short* Bp   = agg + ND;                     // 512*256 bf16
    float* z      = (float*)(Bp + (size_t)KDIM * DIM + 64);  // ND fp32 (pad for OOB-read slack)
    float* e_src  = z + ND;                              // NN
    float* colsum = e_src + NN;                          // DIM
    float* xsum   = colsum + DIM;                        // DIM
    int*   row_ptr = (int*)(xsum + DIM);                 // NN+1
    int*   cursor  = row_ptr + NN + 1;                   // NN
    int*   blkSums = cursor + NN;                        // 256
    int*   csr_src = blkSums + 256;                      // EE

    const int NBLK_N = (NN + 255) / 256;   // 196
    const int NBLK_E = (EE + 255) / 256;   // 6250

    hipMemsetAsync(cursor, 0, (size_t)NN * sizeof(int), stream);
    hipMemsetAsync(colsum, 0, 2 * DIM * sizeof(float), stream);

    // CSR build
    k_count_deg<<<NBLK_E, 256, 0, stream>>>(ei, cursor);
    k_scan1<<<NBLK_N, 256, 0, stream>>>(cursor, row_ptr, blkSums);
    k_scan2<<<1, 256, 0, stream>>>(blkSums, NBLK_N);
    k_scan3<<<NBLK_N, 256, 0, stream>>>(row_ptr, blkSums, cursor);
    k_scatter<<<NBLK_E, 256, 0, stream>>>(ei, cursor, csr_src);

    // x -> bf16 + layer-0 scores
    k_prep<<<NN / 4, 256, 0, stream>>>(x, W_attn + DIM, hx, e_src);

    unsigned short* hbufs[3] = {hx, hA, hB};
    for (int l = 0; l < NLAYER; ++l) {
        unsigned short* h_in  = hbufs[l];
        unsigned short* h_out = hbufs[l + 1 < 3 ? l + 1 : 1];  // l=2 -> hA (hx no longer needed)
        k_packB<<<(KDIM * DIM) / 256, 256, 0, stream>>>(W_sage + (size_t)l * KDIM * DIM, Bp);
        k_aggregate<<<NN / 4, 256, 0, stream>>>(h_in, e_src, row_ptr, csr_src, agg);
        k_gemm_mfma<<<dim3((NN + 127) / 128, 2), 256, 0, stream>>>(
            h_in, agg, Bp, b_sage + (size_t)l * DIM, z);
        const float* wnext = (l < NLAYER - 1) ? (W_attn + (size_t)(l + 1) * KDIM + DIM) : nullptr;
        k_ln_relu<<<NN / 4, 256, 0, stream>>>(z, gamma + (size_t)l * DIM, beta + (size_t)l * DIM,
                                              wnext, h_out, e_src);
    }

    k_colsum_bf16<<<256, 256, 0, stream>>>(hbufs[1], colsum);  // final h lives in hA after l=2
    k_colsum_f32<<<256, 256, 0, stream>>>(x, xsum);
    k_final<<<1, 256, 0, stream>>>(colsum, xsum, W_skip, b_skip, out);
}